// Round 1
// baseline (263.695 us; speedup 1.0000x reference)
//
#include <hip/hip_runtime.h>
#include <math.h>

typedef _Float16 f16;
typedef _Float16 f16x8 __attribute__((ext_vector_type(8)));
typedef _Float16 f16x4 __attribute__((ext_vector_type(4)));
typedef float    f32x4 __attribute__((ext_vector_type(4)));

#define NN 8192        // sequence length per batch
#define DD 64          // feature dim == output dim
#define KT 32          // keys per tile
#define NQB 64         // queries per block
#define KPW 2048       // keys per wave (8192 / 4 waves)
#define NTILES (KPW / KT)   // 64

// per-wave LDS regions (halves)
#define XK_PITCH 72    // natural [key][d] pitch
#define XT_PITCH 40    // transposed [d][key] pitch (32 keys + pad)
#define PS_PITCH 40    // P scratch [q][key] pitch
#define XK_BYTES (KT * XK_PITCH * 2)     // 4608
#define XT_BYTES (DD * XT_PITCH * 2)     // 5120
#define PS_BYTES (NQB * PS_PITCH * 2)    // 5120
#define WAVE_BYTES (XK_BYTES + XT_BYTES + PS_BYTES)  // 14848
#define MAIN_BYTES (4 * WAVE_BYTES)      // 59392
// epilogue union (overlaps wave regions, used after main loop):
#define HL_PITCH 68
#define WL_OFF   (64 * HL_PITCH * 4)     // 17408 (Hl occupies [0, WL_OFF))
// separate small region (never overlapped):
#define MS_OFF   MAIN_BYTES
#define LS_OFF   (MS_OFF + 256 * 4)
#define LST_OFF  (LS_OFF + 256 * 4)
#define SMEM_BYTES (LST_OFF + 64 * 4)    // 61696 B -> 2 blocks/CU

__global__ __launch_bounds__(256, 2)
void gconv_attn(const float* __restrict__ X, const float* __restrict__ W,
                float* __restrict__ out)
{
  __shared__ __align__(16) unsigned char smem[SMEM_BYTES];

  const int tid  = threadIdx.x;
  const int lane = tid & 63;
  const int wave = tid >> 6;
  const int q15  = lane & 15;
  const int quad = lane >> 4;

  const int batch = blockIdx.x >> 7;            // 128 q-tiles per batch
  const int qbase = (blockIdx.x & 127) * NQB;   // within batch
  const float* Xb = X + (size_t)batch * NN * DD;

  f16* Xk = (f16*)(smem + wave * WAVE_BYTES);
  f16* Xt = (f16*)(smem + wave * WAVE_BYTES + XK_BYTES);
  f16* Ps = (f16*)(smem + wave * WAVE_BYTES + XK_BYTES + XT_BYTES);

  // ---- load query fragments (fp32 -> fp16), MFMA B-operand layout ----
  // B[k=d][n=q]: lane holds query (qbase + qt*16 + q15), d = c*32 + quad*8 + j
  f16x8 qf[4][2];
  #pragma unroll
  for (int qt = 0; qt < 4; ++qt) {
    const float* qp = Xb + (size_t)(qbase + qt*16 + q15) * DD + quad*8;
    #pragma unroll
    for (int c = 0; c < 2; ++c) {
      const float4 a = *(const float4*)(qp + c*32);
      const float4 b = *(const float4*)(qp + c*32 + 4);
      f16x8 v;
      v[0]=(f16)a.x; v[1]=(f16)a.y; v[2]=(f16)a.z; v[3]=(f16)a.w;
      v[4]=(f16)b.x; v[5]=(f16)b.y; v[6]=(f16)b.z; v[7]=(f16)b.w;
      qf[qt][c] = v;
    }
  }

  f32x4 acc[4][4];   // [qt][mt]: h^T accumulator, C-layout
  #pragma unroll
  for (int a = 0; a < 4; ++a)
    #pragma unroll
    for (int b = 0; b < 4; ++b)
      acc[a][b] = (f32x4){0.f, 0.f, 0.f, 0.f};
  float mrow[4], lrow[4];
  #pragma unroll
  for (int qt = 0; qt < 4; ++qt) { mrow[qt] = -INFINITY; lrow[qt] = 0.f; }

  const int rk = lane & 31;          // staging: key row within tile
  const int dh = (lane >> 5) * 32;   // staging: d-half

  for (int t = 0; t < NTILES; ++t) {
    const int kbase = wave * KPW + t * KT;

    // ---- stage key tile: fp32 global -> fp16 LDS (natural + swizzled transposed) ----
    {
      const float* src = Xb + (size_t)(kbase + rk) * DD + dh;
      union { f16 h[32]; f16x8 v[4]; } cv;
      #pragma unroll
      for (int c8 = 0; c8 < 8; ++c8) {
        const float4 f = *(const float4*)(src + c8*4);
        cv.h[c8*4+0] = (f16)f.x;
        cv.h[c8*4+1] = (f16)f.y;
        cv.h[c8*4+2] = (f16)f.z;
        cv.h[c8*4+3] = (f16)f.w;
      }
      #pragma unroll
      for (int c = 0; c < 4; ++c)
        *(f16x8*)&Xk[rk*XK_PITCH + dh + c*8] = cv.v[c];
      #pragma unroll
      for (int i = 0; i < 32; ++i) {
        const int d  = dh + i;
        const int bi = (rk >> 3) ^ ((d >> 3) & 3);   // 8-key-block XOR swizzle
        Xt[d*XT_PITCH + bi*8 + (rk & 7)] = cv.h[i];
      }
    }
    // (no barrier: wave-private regions; DS ops are in-order per wave)

    // ---- S^T = K . Q^T : A-frags = key rows ----
    f16x8 ka[2][2];  // [g = key mtile][c = d chunk]
    #pragma unroll
    for (int g = 0; g < 2; ++g)
      #pragma unroll
      for (int c = 0; c < 2; ++c)
        ka[g][c] = *(const f16x8*)&Xk[(g*16 + q15)*XK_PITCH + c*32 + quad*8];

    #pragma unroll
    for (int qt = 0; qt < 4; ++qt) {
      f32x4 st[2];
      #pragma unroll
      for (int g = 0; g < 2; ++g) {
        f32x4 s = (f32x4){0.f, 0.f, 0.f, 0.f};
        s = __builtin_amdgcn_mfma_f32_16x16x32_f16(ka[g][0], qf[qt][0], s, 0, 0, 0);
        s = __builtin_amdgcn_mfma_f32_16x16x32_f16(ka[g][1], qf[qt][1], s, 0, 0, 0);
        st[g] = s;   // st[g][r] = S[key = g*16+quad*4+r][query = qt*16+q15]
      }
      // ---- online softmax (per query column) ----
      float tmax = st[0][0];
      #pragma unroll
      for (int g = 0; g < 2; ++g)
        #pragma unroll
        for (int rr = 0; rr < 4; ++rr) tmax = fmaxf(tmax, st[g][rr]);
      tmax = fmaxf(tmax, __shfl_xor(tmax, 16));
      tmax = fmaxf(tmax, __shfl_xor(tmax, 32));
      const float mn = fmaxf(mrow[qt], tmax);
      float ls = 0.f;
      #pragma unroll
      for (int g = 0; g < 2; ++g)
        #pragma unroll
        for (int rr = 0; rr < 4; ++rr) {
          const float p = __expf(st[g][rr] - mn);
          st[g][rr] = p;
          ls += p;
        }
      ls += __shfl_xor(ls, 16);
      ls += __shfl_xor(ls, 32);
      if (__ballot(mn > mrow[qt])) {          // wave-uniform branch
        const float al = __expf(mrow[qt] - mn);
        lrow[qt] = lrow[qt]*al + ls;
        #pragma unroll
        for (int mt = 0; mt < 4; ++mt)
          #pragma unroll
          for (int rr = 0; rr < 4; ++rr) acc[qt][mt][rr] *= al;
        mrow[qt] = mn;
      } else {
        lrow[qt] += ls;
      }
      // ---- write P (fp16) to wave-private scratch, [q][key] ----
      #pragma unroll
      for (int g = 0; g < 2; ++g) {
        f16x4 ph;
        #pragma unroll
        for (int rr = 0; rr < 4; ++rr) ph[rr] = (f16)st[g][rr];
        *(f16x4*)&Ps[(qt*16 + q15)*PS_PITCH + g*16 + quad*4] = ph;
      }
    }

    // ---- h^T += V^T . P^T ----
    f16x8 va[4];  // A-frags from transposed tile: lane holds d = mt*16+q15, keys quad*8..+7
    #pragma unroll
    for (int mt = 0; mt < 4; ++mt) {
      const int d  = mt*16 + q15;
      const int bi = quad ^ ((d >> 3) & 3);
      va[mt] = *(const f16x8*)&Xt[d*XT_PITCH + bi*8];
    }
    #pragma unroll
    for (int qt = 0; qt < 4; ++qt) {
      const f16x8 pf = *(const f16x8*)&Ps[(qt*16 + q15)*PS_PITCH + quad*8];
      #pragma unroll
      for (int mt = 0; mt < 4; ++mt)
        acc[qt][mt] = __builtin_amdgcn_mfma_f32_16x16x32_f16(va[mt], pf, acc[qt][mt], 0, 0, 0);
    }
  }

  // ================= merge partials across the 4 key-split waves =================
  __syncthreads();
  float* Mscr  = (float*)(smem + MS_OFF);
  float* Lscr  = (float*)(smem + LS_OFF);
  float* Lstar = (float*)(smem + LST_OFF);
  float* Hl    = (float*)(smem + 0);
  float* Wl    = (float*)(smem + WL_OFF);

  if (quad == 0) {
    #pragma unroll
    for (int qt = 0; qt < 4; ++qt) {
      Mscr[wave*64 + qt*16 + q15] = mrow[qt];
      Lscr[wave*64 + qt*16 + q15] = lrow[qt];
    }
  }
  for (int i = tid; i < 64*HL_PITCH; i += 256) Hl[i] = 0.f;
  for (int i = tid; i < 64*64; i += 256) Wl[(i >> 6)*HL_PITCH + (i & 63)] = W[i];
  __syncthreads();

  #pragma unroll
  for (int qt = 0; qt < 4; ++qt) {
    const int qq = qt*16 + q15;
    const float m0 = Mscr[0*64+qq], m1 = Mscr[1*64+qq];
    const float m2 = Mscr[2*64+qq], m3 = Mscr[3*64+qq];
    const float ms = fmaxf(fmaxf(m0, m1), fmaxf(m2, m3));
    const float lt = __expf(m0-ms)*Lscr[0*64+qq] + __expf(m1-ms)*Lscr[1*64+qq]
                   + __expf(m2-ms)*Lscr[2*64+qq] + __expf(m3-ms)*Lscr[3*64+qq];
    if (wave == 0 && quad == 0) Lstar[qq] = lt;
    const float sc = __expf(mrow[qt] - ms);
    #pragma unroll
    for (int mt = 0; mt < 4; ++mt)
      #pragma unroll
      for (int rr = 0; rr < 4; ++rr)
        atomicAdd(&Hl[qq*HL_PITCH + mt*16 + quad*4 + rr], acc[qt][mt][rr] * sc);
  }
  __syncthreads();

  // ================= output projection: out = (H / l) . W =================
  {
    const int qq = tid >> 2;
    const int og = (tid & 3) * 16;
    f32x4 oacc[4];
    #pragma unroll
    for (int i = 0; i < 4; ++i) oacc[i] = (f32x4){0.f, 0.f, 0.f, 0.f};
    for (int d = 0; d < 64; ++d) {
      const float h = Hl[qq*HL_PITCH + d];
      const f32x4* wr = (const f32x4*)&Wl[d*HL_PITCH + og];
      #pragma unroll
      for (int i = 0; i < 4; ++i) oacc[i] += h * wr[i];
    }
    const float inv = 1.0f / Lstar[qq];
    float* op = out + ((size_t)batch * NN + qbase + qq) * DD + og;
    #pragma unroll
    for (int i = 0; i < 4; ++i) {
      f32x4 v = oacc[i] * inv;
      *(f32x4*)(op + i*4) = v;
    }
  }
}

extern "C" void kernel_launch(void* const* d_in, const int* in_sizes, int n_in,
                              void* d_out, int out_size, void* d_ws, size_t ws_size,
                              hipStream_t stream) {
  const float* X = (const float*)d_in[0];   // [4, 8192, 64] fp32
  const float* W = (const float*)d_in[1];   // [64, 64] fp32
  float* out = (float*)d_out;               // [4, 8192, 64] fp32
  dim3 grid(512), block(256);               // 512 q-tiles of 64 queries
  gconv_attn<<<grid, block, 0, stream>>>(X, W, out);
}